// Round 1
// baseline (62350.317 us; speedup 1.0000x reference)
//
#include <hip/hip_runtime.h>
#include <hip/hip_bf16.h>

// Shapes (fixed by the problem)
#define B    32
#define TIN  16
#define X    8192
#define H    64
#define F    128
#define K    5
#define DEPTH 3
#define TOUT 32
#define TILE_X 32

__device__ __forceinline__ float gelu_exact(float z) {
    return 0.5f * z * (1.0f + erff(z * 0.70710678118654752f));
}

// ---------------- encoder: psi[b,x,h] = sum_t x[b,t,x]*enc_w[h,t]+enc_b[h], then per-(b,x) normalize (ddof=1, +1e-6 on sd)
__global__ __launch_bounds__(256) void k_encoder(const float* __restrict__ xin,
                                                 const float* __restrict__ enc_w,
                                                 const float* __restrict__ enc_b,
                                                 float* __restrict__ psi) {
    const int b  = blockIdx.y;
    const int x0 = blockIdx.x * 64;
    __shared__ float s_x[TIN][64];   // [t][x_local]
    __shared__ float s_w[TIN][H];    // transposed enc_w: s_w[t][h]
    __shared__ float s_p[64][H];
    const int tid = threadIdx.x;

    for (int idx = tid; idx < TIN * 64; idx += 256) {
        int t = idx >> 6, xl = idx & 63;
        s_x[t][xl] = xin[((size_t)b * TIN + t) * X + x0 + xl];
    }
    for (int idx = tid; idx < TIN * H; idx += 256) {
        int t = idx >> 6, h = idx & 63;      // idx = t*64 + h
        s_w[t][h] = enc_w[h * TIN + t];
    }
    __syncthreads();

    {
        int h = tid & 63, grp = tid >> 6;    // 4 groups x 16 rows
        float bias = enc_b[h];
        for (int r = 0; r < 16; ++r) {
            int xl = grp * 16 + r;
            float acc = bias;
            #pragma unroll
            for (int t = 0; t < TIN; ++t) acc += s_x[t][xl] * s_w[t][h];
            s_p[xl][h] = acc;
        }
    }
    __syncthreads();

    {
        int lane = tid & 63, wv = tid >> 6;
        for (int r = 0; r < 16; ++r) {
            int xl = wv * 16 + r;
            float v = s_p[xl][lane];
            float s = v;
            #pragma unroll
            for (int off = 32; off; off >>= 1) s += __shfl_xor(s, off);
            float mu = s * (1.0f / 64.0f);
            float dv = v - mu;
            float q = dv * dv;
            #pragma unroll
            for (int off = 32; off; off >>= 1) q += __shfl_xor(q, off);
            float sd = sqrtf(q * (1.0f / 63.0f)) + 1e-6f;   // ddof=1, +1e-6 on sd
            psi[((size_t)b * X + x0 + xl) * H + lane] = dv / sd;
        }
    }
}

// ---------------- one depth layer: conv(K=5,pad=2) -> MLP(64->128 gelu ->64) -> residual -> LN -> clip
__global__ __launch_bounds__(256) void k_layer(const float* __restrict__ pin,
                                               float* __restrict__ pout,
                                               const float* __restrict__ cw,   // [H][H][K] for this depth
                                               const float* __restrict__ cb,
                                               const float* __restrict__ w1,   // [F][H]
                                               const float* __restrict__ b1,
                                               const float* __restrict__ w2,   // [H][F]
                                               const float* __restrict__ b2,
                                               const float* __restrict__ g,
                                               const float* __restrict__ bt) {
    const int b  = blockIdx.y;
    const int x0 = blockIdx.x * TILE_X;
    __shared__ float s_psi[TILE_X + 4][H];   // rows map x0-2 .. x0+TILE_X+1
    __shared__ float s_h[TILE_X][H];
    __shared__ float s_m[TILE_X][F];
    const int tid = threadIdx.x;

    // phase 1: load psi tile (+halo, zero-pad at batch-row boundaries)
    for (int idx = tid; idx < (TILE_X + 4) * H; idx += 256) {
        int r = idx >> 6, h = idx & 63;
        int gx = x0 + r - 2;
        float v = 0.0f;
        if (gx >= 0 && gx < X) v = pin[((size_t)b * X + gx) * H + h];
        s_psi[r][h] = v;
    }
    __syncthreads();

    // phase 2: conv. thread: o = tid&63, grp = tid>>6 handles 8 output rows
    {
        int o = tid & 63, grp = tid >> 6;
        float acc[8];
        float bias = cb[o];
        #pragma unroll
        for (int r = 0; r < 8; ++r) acc[r] = bias;
        const float* wo = cw + o * (H * K);
        for (int d = 0; d < H; ++d) {
            float p[12];
            #pragma unroll
            for (int j = 0; j < 12; ++j) p[j] = s_psi[grp * 8 + j][d];
            const float* wd = wo + d * K;
            float w0 = wd[0], wk1 = wd[1], wk2 = wd[2], wk3 = wd[3], wk4 = wd[4];
            #pragma unroll
            for (int r = 0; r < 8; ++r)
                acc[r] += p[r] * w0 + p[r + 1] * wk1 + p[r + 2] * wk2 + p[r + 3] * wk3 + p[r + 4] * wk4;
        }
        #pragma unroll
        for (int r = 0; r < 8; ++r) s_h[grp * 8 + r][o] = acc[r];
    }
    __syncthreads();

    // phase 3: mlp1 + gelu. thread handles f0=tid&63 and f0+64 for 8 rows
    {
        int f0 = tid & 63, grp = tid >> 6;
        int f1 = f0 + 64;
        float acc0[8], acc1[8];
        float bias0 = b1[f0], bias1 = b1[f1];
        #pragma unroll
        for (int r = 0; r < 8; ++r) { acc0[r] = bias0; acc1[r] = bias1; }
        const float* w1a = w1 + f0 * H;
        const float* w1b = w1 + f1 * H;
        for (int d = 0; d < H; ++d) {
            float p[8];
            #pragma unroll
            for (int j = 0; j < 8; ++j) p[j] = s_h[grp * 8 + j][d];
            float wa = w1a[d], wb = w1b[d];
            #pragma unroll
            for (int r = 0; r < 8; ++r) { acc0[r] += p[r] * wa; acc1[r] += p[r] * wb; }
        }
        #pragma unroll
        for (int r = 0; r < 8; ++r) {
            s_m[grp * 8 + r][f0] = gelu_exact(acc0[r]);
            s_m[grp * 8 + r][f1] = gelu_exact(acc1[r]);
        }
    }
    __syncthreads();

    // phase 4: mlp2 + residual -> write s into s_h (reused)
    {
        int d = tid & 63, grp = tid >> 6;
        float acc[8];
        float bias = b2[d];
        #pragma unroll
        for (int r = 0; r < 8; ++r) acc[r] = bias;
        const float* w2d = w2 + d * F;
        for (int f = 0; f < F; ++f) {
            float wv = w2d[f];
            float p[8];
            #pragma unroll
            for (int j = 0; j < 8; ++j) p[j] = s_m[grp * 8 + j][f];
            #pragma unroll
            for (int r = 0; r < 8; ++r) acc[r] += p[r] * wv;
        }
        #pragma unroll
        for (int r = 0; r < 8; ++r) {
            int xr = grp * 8 + r;
            s_h[xr][d] = s_psi[xr + 2][d] + acc[r];
        }
    }
    __syncthreads();

    // phase 5: LN (ddof=0, eps inside rsqrt) + clip + store
    {
        int lane = tid & 63, wv = tid >> 6;
        float gg = g[lane], bb = bt[lane];
        for (int rr = 0; rr < 8; ++rr) {
            int xr = wv * 8 + rr;
            float v = s_h[xr][lane];
            float s = v;
            #pragma unroll
            for (int off = 32; off; off >>= 1) s += __shfl_xor(s, off);
            float mu = s * (1.0f / 64.0f);
            float dv = v - mu;
            float q = dv * dv;
            #pragma unroll
            for (int off = 32; off; off >>= 1) q += __shfl_xor(q, off);
            float var = q * (1.0f / 64.0f);
            float o = dv * rsqrtf(var + 1e-5f) * gg + bb;
            o = fminf(10.0f, fmaxf(-10.0f, o));
            pout[((size_t)b * X + x0 + xr) * H + lane] = o;
        }
    }
}

// ---------------- decoder head for one scan step: y = (gelu(psi@dec_w1^T+b1)@dec_w2^T+b2)
__global__ __launch_bounds__(256) void k_dec(const float* __restrict__ psi,
                                             const float* __restrict__ w1,  // [H][H]
                                             const float* __restrict__ b1,
                                             const float* __restrict__ w2,  // [1][H]
                                             const float* __restrict__ b2,
                                             float* __restrict__ out, int step) {
    const int b  = blockIdx.y;
    const int x0 = blockIdx.x * 64;
    __shared__ float s_p[64][H];
    __shared__ float s_y[64][H];
    const int tid = threadIdx.x;

    for (int idx = tid; idx < 64 * H; idx += 256) {
        int r = idx >> 6, h = idx & 63;
        s_p[r][h] = psi[((size_t)b * X + x0 + r) * H + h];
    }
    __syncthreads();

    {
        int h = tid & 63, grp = tid >> 6;    // 4 groups x 16 rows
        const float* w1h = w1 + h * H;
        float acc[16];
        float bias = b1[h];
        #pragma unroll
        for (int r = 0; r < 16; ++r) acc[r] = bias;
        for (int d = 0; d < H; ++d) {
            float wv = w1h[d];
            #pragma unroll
            for (int r = 0; r < 16; ++r) acc[r] += s_p[grp * 16 + r][d] * wv;
        }
        #pragma unroll
        for (int r = 0; r < 16; ++r) s_y[grp * 16 + r][h] = gelu_exact(acc[r]);
    }
    __syncthreads();

    {
        int lane = tid & 63, wv = tid >> 6;
        float w2v = w2[lane];
        float bias = b2[0];
        for (int r = 0; r < 16; ++r) {
            int xr = wv * 16 + r;
            float v = s_y[xr][lane] * w2v;
            #pragma unroll
            for (int off = 32; off; off >>= 1) v += __shfl_xor(v, off);
            if (lane == 0)
                out[((size_t)b * TOUT + step) * X + x0 + xr] = v + bias;
        }
    }
}

extern "C" void kernel_launch(void* const* d_in, const int* in_sizes, int n_in,
                              void* d_out, int out_size, void* d_ws, size_t ws_size,
                              hipStream_t stream) {
    const float* xin    = (const float*)d_in[0];
    const float* enc_w  = (const float*)d_in[1];
    const float* enc_b  = (const float*)d_in[2];
    const float* conv_w = (const float*)d_in[3];
    const float* conv_b = (const float*)d_in[4];
    const float* mlp_w1 = (const float*)d_in[5];
    const float* mlp_b1 = (const float*)d_in[6];
    const float* mlp_w2 = (const float*)d_in[7];
    const float* mlp_b2 = (const float*)d_in[8];
    const float* ln_g   = (const float*)d_in[9];
    const float* ln_b   = (const float*)d_in[10];
    const float* dec_w1 = (const float*)d_in[11];
    const float* dec_b1 = (const float*)d_in[12];
    const float* dec_w2 = (const float*)d_in[13];
    const float* dec_b2 = (const float*)d_in[14];
    float* out = (float*)d_out;

    float* psiA = (float*)d_ws;
    float* psiB = psiA + (size_t)B * X * H;   // 2 x 64 MB ping-pong

    dim3 blk(256);
    k_encoder<<<dim3(X / 64, B), blk, 0, stream>>>(xin, enc_w, enc_b, psiA);

    const float* cur = psiA;
    float* nxt = psiB;
    for (int t = 0; t < TOUT; ++t) {
        for (int i = 0; i < DEPTH; ++i) {
            k_layer<<<dim3(X / TILE_X, B), blk, 0, stream>>>(
                cur, nxt,
                conv_w + (size_t)i * H * H * K, conv_b + i * H,
                mlp_w1 + (size_t)i * F * H,     mlp_b1 + i * F,
                mlp_w2 + (size_t)i * H * F,     mlp_b2 + i * H,
                ln_g + i * H,                    ln_b + i * H);
            float* tmp = (float*)cur; cur = nxt; nxt = tmp;
        }
        k_dec<<<dim3(X / 64, B), blk, 0, stream>>>(cur, dec_w1, dec_b1, dec_w2, dec_b2, out, t);
    }
}

// Round 2
// 34274.878 us; speedup vs baseline: 1.8191x; 1.8191x over previous
//
#include <hip/hip_runtime.h>
#include <hip/hip_bf16.h>

#define B_   32
#define TIN  16
#define X_   8192
#define H_   64
#define F_   128
#define K_   5
#define DEPTH 3
#define TOUT 32
#define TILE 64

typedef __attribute__((ext_vector_type(8))) short short8;
typedef __attribute__((ext_vector_type(4))) short short4v;
typedef __attribute__((ext_vector_type(4))) float f32x4;

__device__ __forceinline__ short f2bf(float x) {           // RNE f32 -> bf16 bits
    union { float f; unsigned u; } a; a.f = x;
    unsigned r = (a.u + 0x7FFFu + ((a.u >> 16) & 1u)) >> 16;
    return (short)r;
}
__device__ __forceinline__ float bf2f(short s) {
    union { unsigned u; float f; } a; a.u = ((unsigned)(unsigned short)s) << 16;
    return a.f;
}
__device__ __forceinline__ float gelu_exact(float z) {
    return 0.5f * z * (1.0f + erff(z * 0.70710678118654752f));
}

// swizzled LDS address: row stride rb bytes, XOR (row&7)<<4 kills 128B-stride bank conflicts
__device__ __forceinline__ short* lp(short* base, int row, int cb, int rb) {
    return (short*)((char*)base + row * rb + (cb ^ ((row & 7) << 4)));
}
// A-fragment (16x32 bf16) from swizzled LDS: caller passes full array row (incl. lane&15)
__device__ __forceinline__ short8 lda(const short* base, int row, int kt, int rb, int lane) {
    return *(const short8*)((const char*)base + row * rb +
                            ((kt * 64 + ((lane >> 4) << 4)) ^ ((row & 7) << 4)));
}
// B-fragment from global weights W[N][K] bf16 row-major; kb = K*2 bytes
__device__ __forceinline__ short8 ldw(const short* w, int nt, int kt, int kb, int lane) {
    return *(const short8*)((const char*)w + (nt * 16 + (lane & 15)) * kb +
                            kt * 64 + ((lane >> 4) << 4));
}

// ---------------- weight prep: fp32 -> bf16 hi/lo planes in d_ws ----------------
__global__ __launch_bounds__(256) void k_prep_lin(const float* __restrict__ s,
                                                  short* __restrict__ hi,
                                                  short* __restrict__ lo, int n) {
    int i = blockIdx.x * 256 + threadIdx.x;
    if (i < n) {
        float v = s[i];
        short h = f2bf(v);
        hi[i] = h;
        lo[i] = f2bf(v - bf2f(h));
    }
}
// conv_w [3][64o][64d][5k] -> [3][5][64o][64d] per plane
__global__ __launch_bounds__(256) void k_prep_conv(const float* __restrict__ s,
                                                   short* __restrict__ hi,
                                                   short* __restrict__ lo) {
    int t = blockIdx.x * 256 + threadIdx.x;
    if (t < DEPTH * 64 * 64 * K_) {
        int k = t % 5, d = (t / 5) % 64, o = (t / 320) % 64, i = t / 20480;
        float v = s[t];
        int dst = ((i * 5 + k) * 64 + o) * 64 + d;
        short h = f2bf(v);
        hi[dst] = h;
        lo[dst] = f2bf(v - bf2f(h));
    }
}

// ---------------- encoder (runs once; fp32 VALU is fine) ----------------
__global__ __launch_bounds__(256) void k_encoder(const float* __restrict__ xin,
                                                 const float* __restrict__ enc_w,
                                                 const float* __restrict__ enc_b,
                                                 float* __restrict__ psi) {
    const int b  = blockIdx.y;
    const int x0 = blockIdx.x * 64;
    __shared__ float s_x[TIN][64];
    __shared__ float s_w[TIN][H_];
    __shared__ float s_p[64][H_];
    const int tid = threadIdx.x;

    for (int idx = tid; idx < TIN * 64; idx += 256) {
        int t = idx >> 6, xl = idx & 63;
        s_x[t][xl] = xin[((size_t)b * TIN + t) * X_ + x0 + xl];
    }
    for (int idx = tid; idx < TIN * H_; idx += 256) {
        int t = idx >> 6, h = idx & 63;
        s_w[t][h] = enc_w[h * TIN + t];
    }
    __syncthreads();
    {
        int h = tid & 63, grp = tid >> 6;
        float bias = enc_b[h];
        for (int r = 0; r < 16; ++r) {
            int xl = grp * 16 + r;
            float acc = bias;
            #pragma unroll
            for (int t = 0; t < TIN; ++t) acc += s_x[t][xl] * s_w[t][h];
            s_p[xl][h] = acc;
        }
    }
    __syncthreads();
    {
        int lane = tid & 63, wv = tid >> 6;
        for (int r = 0; r < 16; ++r) {
            int xl = wv * 16 + r;
            float v = s_p[xl][lane];
            float s = v;
            #pragma unroll
            for (int off = 32; off; off >>= 1) s += __shfl_xor(s, off);
            float mu = s * (1.0f / 64.0f);
            float dv = v - mu;
            float q = dv * dv;
            #pragma unroll
            for (int off = 32; off; off >>= 1) q += __shfl_xor(q, off);
            float sd = sqrtf(q * (1.0f / 63.0f)) + 1e-6f;
            psi[((size_t)b * X_ + x0 + xl) * H_ + lane] = dv / sd;
        }
    }
}

// ---------------- fused layer: conv(K=5) -> MLP(64->128 gelu ->64) -> resid -> LN -> clip
// split-bf16 (3 passes: hi*hi, lo*hi, hi*lo) => fp32-equivalent accuracy
__global__ __launch_bounds__(256) void k_layer(const float* __restrict__ pin,
                                               float* __restrict__ pout,
                                               const short* __restrict__ cw_hi,
                                               const short* __restrict__ cw_lo,  // [5][64][64]
                                               const float* __restrict__ cb,
                                               const short* __restrict__ w1_hi,
                                               const short* __restrict__ w1_lo,  // [128][64]
                                               const float* __restrict__ b1,
                                               const short* __restrict__ w2_hi,
                                               const short* __restrict__ w2_lo,  // [64][128]
                                               const float* __restrict__ b2,
                                               const float* __restrict__ g,
                                               const float* __restrict__ bt) {
    __shared__ __align__(16) short sA[2][68 * 64];    // psi tile + halo, hi/lo
    __shared__ __align__(16) short sH[2][64 * 64];    // conv out
    __shared__ __align__(16) short sM[2][64 * 128];   // mlp1 out (gelu'd)

    const int tid  = threadIdx.x;
    const int b    = blockIdx.y;
    const int x0   = blockIdx.x * TILE;
    const int lane = tid & 63, wv = tid >> 6;
    const int wbase = wv * 16;
    const int l15 = lane & 15, l4 = lane >> 4;

    // ---- stage psi rows [x0-2, x0+66) as swizzled bf16 hi/lo
    for (int idx = tid; idx < 68 * 16; idx += 256) {
        int r = idx >> 4, c4 = idx & 15;
        int gx = x0 + r - 2;
        float4 v = make_float4(0.f, 0.f, 0.f, 0.f);
        if (gx >= 0 && gx < X_) v = *(const float4*)&pin[((size_t)b * X_ + gx) * H_ + c4 * 4];
        float vv[4] = {v.x, v.y, v.z, v.w};
        short4v hi, lo;
        #pragma unroll
        for (int q = 0; q < 4; ++q) {
            short h = f2bf(vv[q]);
            hi[q] = h;
            lo[q] = f2bf(vv[q] - bf2f(h));
        }
        *(short4v*)lp(sA[0], r, c4 * 8, 128) = hi;
        *(short4v*)lp(sA[1], r, c4 * 8, 128) = lo;
    }
    __syncthreads();
    // everything below is wave-private (wave owns rows [wbase, wbase+16))

    // ---- conv: 5 shifted GEMMs, K=64 each
    f32x4 acc[4];
    #pragma unroll
    for (int nt = 0; nt < 4; ++nt) {
        float bb = cb[nt * 16 + l15];
        acc[nt] = (f32x4){bb, bb, bb, bb};
    }
    #pragma unroll
    for (int pass = 0; pass < 3; ++pass) {
        const short* Ap = (pass == 1) ? sA[1] : sA[0];
        const short* Wp = (pass == 2) ? cw_lo : cw_hi;
        #pragma unroll
        for (int k = 0; k < K_; ++k) {
            #pragma unroll
            for (int kt = 0; kt < 2; ++kt) {
                short8 a = lda(Ap, wbase + l15 + k, kt, 128, lane);
                #pragma unroll
                for (int nt = 0; nt < 4; ++nt) {
                    short8 bf = ldw(Wp + k * 4096, nt, kt, 128, lane);
                    acc[nt] = __builtin_amdgcn_mfma_f32_16x16x32_bf16(a, bf, acc[nt], 0, 0, 0);
                }
            }
        }
    }
    // write h (hi/lo) to LDS
    #pragma unroll
    for (int nt = 0; nt < 4; ++nt) {
        int col = nt * 16 + l15;
        #pragma unroll
        for (int j = 0; j < 4; ++j) {
            int row = wbase + (l4 << 2) + j;
            float v = acc[nt][j];
            short h = f2bf(v);
            *lp(sH[0], row, col * 2, 128) = h;
            *lp(sH[1], row, col * 2, 128) = f2bf(v - bf2f(h));
        }
    }

    // ---- mlp1: [64]->[128], gelu
    f32x4 m8[8];
    #pragma unroll
    for (int nt = 0; nt < 8; ++nt) {
        float bb = b1[nt * 16 + l15];
        m8[nt] = (f32x4){bb, bb, bb, bb};
    }
    #pragma unroll
    for (int pass = 0; pass < 3; ++pass) {
        const short* Ap = (pass == 1) ? sH[1] : sH[0];
        const short* Wp = (pass == 2) ? w1_lo : w1_hi;
        #pragma unroll
        for (int kt = 0; kt < 2; ++kt) {
            short8 a = lda(Ap, wbase + l15, kt, 128, lane);
            #pragma unroll
            for (int nt = 0; nt < 8; ++nt) {
                short8 bf = ldw(Wp, nt, kt, 128, lane);
                m8[nt] = __builtin_amdgcn_mfma_f32_16x16x32_bf16(a, bf, m8[nt], 0, 0, 0);
            }
        }
    }
    #pragma unroll
    for (int nt = 0; nt < 8; ++nt) {
        int col = nt * 16 + l15;
        #pragma unroll
        for (int j = 0; j < 4; ++j) {
            int row = wbase + (l4 << 2) + j;
            float v = gelu_exact(m8[nt][j]);
            short h = f2bf(v);
            *lp(sM[0], row, col * 2, 256) = h;
            *lp(sM[1], row, col * 2, 256) = f2bf(v - bf2f(h));
        }
    }

    // ---- mlp2: [128]->[64]
    f32x4 o4[4];
    #pragma unroll
    for (int nt = 0; nt < 4; ++nt) {
        float bb = b2[nt * 16 + l15];
        o4[nt] = (f32x4){bb, bb, bb, bb};
    }
    #pragma unroll
    for (int pass = 0; pass < 3; ++pass) {
        const short* Ap = (pass == 1) ? sM[1] : sM[0];
        const short* Wp = (pass == 2) ? w2_lo : w2_hi;
        #pragma unroll
        for (int kt = 0; kt < 4; ++kt) {
            short8 a = lda(Ap, wbase + l15, kt, 256, lane);
            #pragma unroll
            for (int nt = 0; nt < 4; ++nt) {
                short8 bf = ldw(Wp, nt, kt, 256, lane);
                o4[nt] = __builtin_amdgcn_mfma_f32_16x16x32_bf16(a, bf, o4[nt], 0, 0, 0);
            }
        }
    }

    // ---- residual (re-read psi from global/L2) + LN + clip + store
    #pragma unroll
    for (int j = 0; j < 4; ++j) {
        int R = wbase + (l4 << 2) + j;
        size_t grow = ((size_t)b * X_ + x0 + R) * H_;
        float v[4];
        #pragma unroll
        for (int nt = 0; nt < 4; ++nt) v[nt] = o4[nt][j] + pin[grow + nt * 16 + l15];
        float s = v[0] + v[1] + v[2] + v[3];
        #pragma unroll
        for (int m = 1; m < 16; m <<= 1) s += __shfl_xor(s, m);
        float mu = s * (1.0f / 64.0f);
        float q = 0.f;
        #pragma unroll
        for (int nt = 0; nt < 4; ++nt) { v[nt] -= mu; q += v[nt] * v[nt]; }
        #pragma unroll
        for (int m = 1; m < 16; m <<= 1) q += __shfl_xor(q, m);
        float rs = rsqrtf(q * (1.0f / 64.0f) + 1e-5f);
        #pragma unroll
        for (int nt = 0; nt < 4; ++nt) {
            int col = nt * 16 + l15;
            float o = v[nt] * rs * g[col] + bt[col];
            o = fminf(10.0f, fmaxf(-10.0f, o));
            pout[grow + col] = o;
        }
    }
}

// ---------------- decoder head (plain bf16, error doesn't accumulate) ----------------
__global__ __launch_bounds__(256) void k_dec(const float* __restrict__ psi,
                                             const short* __restrict__ d1_hi,  // [64][64]
                                             const float* __restrict__ b1d,
                                             const float* __restrict__ w2d,
                                             const float* __restrict__ b2d,
                                             float* __restrict__ out, int step) {
    __shared__ __align__(16) short sD[64 * 64];
    const int tid  = threadIdx.x;
    const int b    = blockIdx.y;
    const int x0   = blockIdx.x * TILE;
    const int lane = tid & 63, wv = tid >> 6;
    const int wbase = wv * 16;
    const int l15 = lane & 15, l4 = lane >> 4;

    for (int idx = tid; idx < 64 * 16; idx += 256) {
        int r = idx >> 4, c4 = idx & 15;
        float4 v = *(const float4*)&psi[((size_t)b * X_ + x0 + r) * H_ + c4 * 4];
        float vv[4] = {v.x, v.y, v.z, v.w};
        short4v hi;
        #pragma unroll
        for (int q = 0; q < 4; ++q) hi[q] = f2bf(vv[q]);
        *(short4v*)lp(sD, r, c4 * 8, 128) = hi;
    }
    __syncthreads();

    f32x4 acc[4];
    #pragma unroll
    for (int nt = 0; nt < 4; ++nt) {
        float bb = b1d[nt * 16 + l15];
        acc[nt] = (f32x4){bb, bb, bb, bb};
    }
    #pragma unroll
    for (int kt = 0; kt < 2; ++kt) {
        short8 a = lda(sD, wbase + l15, kt, 128, lane);
        #pragma unroll
        for (int nt = 0; nt < 4; ++nt) {
            short8 bf = ldw(d1_hi, nt, kt, 128, lane);
            acc[nt] = __builtin_amdgcn_mfma_f32_16x16x32_bf16(a, bf, acc[nt], 0, 0, 0);
        }
    }
    float w2v[4];
    #pragma unroll
    for (int nt = 0; nt < 4; ++nt) w2v[nt] = w2d[nt * 16 + l15];
    float bb = b2d[0];
    #pragma unroll
    for (int j = 0; j < 4; ++j) {
        int R = wbase + (l4 << 2) + j;
        float s = 0.f;
        #pragma unroll
        for (int nt = 0; nt < 4; ++nt) s += gelu_exact(acc[nt][j]) * w2v[nt];
        #pragma unroll
        for (int m = 1; m < 16; m <<= 1) s += __shfl_xor(s, m);
        if (l15 == 0) out[((size_t)b * TOUT + step) * X_ + x0 + R] = s + bb;
    }
}

extern "C" void kernel_launch(void* const* d_in, const int* in_sizes, int n_in,
                              void* d_out, int out_size, void* d_ws, size_t ws_size,
                              hipStream_t stream) {
    const float* xin    = (const float*)d_in[0];
    const float* enc_w  = (const float*)d_in[1];
    const float* enc_b  = (const float*)d_in[2];
    const float* conv_w = (const float*)d_in[3];
    const float* conv_b = (const float*)d_in[4];
    const float* mlp_w1 = (const float*)d_in[5];
    const float* mlp_b1 = (const float*)d_in[6];
    const float* mlp_w2 = (const float*)d_in[7];
    const float* mlp_b2 = (const float*)d_in[8];
    const float* ln_g   = (const float*)d_in[9];
    const float* ln_b   = (const float*)d_in[10];
    const float* dec_w1 = (const float*)d_in[11];
    const float* dec_b1 = (const float*)d_in[12];
    const float* dec_w2 = (const float*)d_in[13];
    const float* dec_b2 = (const float*)d_in[14];
    float* out = (float*)d_out;

    const size_t PSI = (size_t)B_ * X_ * H_;
    float* psiA = (float*)d_ws;
    float* psiB = psiA + PSI;
    short* wb    = (short*)(psiB + PSI);
    short* cw_hi = wb;                  // [3][5][64][64]
    short* cw_lo = cw_hi + 61440;
    short* w1_hi = cw_lo + 61440;       // [3][128][64]
    short* w1_lo = w1_hi + 24576;
    short* w2_hi = w1_lo + 24576;       // [3][64][128]
    short* w2_lo = w2_hi + 24576;
    short* d1_hi = w2_lo + 24576;       // [64][64]
    short* d1_lo = d1_hi + 4096;
    (void)d1_lo; (void)ws_size; (void)n_in; (void)in_sizes; (void)out_size;

    k_prep_conv<<<240, 256, 0, stream>>>(conv_w, cw_hi, cw_lo);
    k_prep_lin<<<96, 256, 0, stream>>>(mlp_w1, w1_hi, w1_lo, 24576);
    k_prep_lin<<<96, 256, 0, stream>>>(mlp_w2, w2_hi, w2_lo, 24576);
    k_prep_lin<<<16, 256, 0, stream>>>(dec_w1, d1_hi, d1_lo, 4096);

    k_encoder<<<dim3(X_ / 64, B_), 256, 0, stream>>>(xin, enc_w, enc_b, psiA);

    const float* cur = psiA;
    float* nxt = psiB;
    for (int t = 0; t < TOUT; ++t) {
        for (int i = 0; i < DEPTH; ++i) {
            k_layer<<<dim3(X_ / TILE, B_), 256, 0, stream>>>(
                cur, nxt,
                cw_hi + i * 20480, cw_lo + i * 20480, conv_b + i * H_,
                w1_hi + i * 8192,  w1_lo + i * 8192,  mlp_b1 + i * F_,
                w2_hi + i * 8192,  w2_lo + i * 8192,  mlp_b2 + i * H_,
                ln_g + i * H_, ln_b + i * H_);
            float* tmp = (float*)cur; cur = nxt; nxt = tmp;
        }
        k_dec<<<dim3(X_ / TILE, B_), 256, 0, stream>>>(cur, d1_hi, dec_b1, dec_w2, dec_b2, out, t);
    }
}

// Round 3
// 14696.793 us; speedup vs baseline: 4.2424x; 2.3321x over previous
//
#include <hip/hip_runtime.h>
#include <hip/hip_bf16.h>

#define B_   32
#define TIN  16
#define X_   8192
#define H_   64
#define F_   128
#define K_   5
#define DEPTH 3
#define TOUT 32
#define TILE 64

typedef __attribute__((ext_vector_type(8))) _Float16 h16x8;
typedef __attribute__((ext_vector_type(4))) _Float16 h16x4;
typedef __attribute__((ext_vector_type(4))) float f32x4;

__device__ __forceinline__ float gelu_exact(float z) {
    return 0.5f * z * (1.0f + erff(z * 0.70710678118654752f));
}

// swizzled LDS address: row stride rb bytes, XOR (row&7)<<4 kills 128B-stride bank conflicts
__device__ __forceinline__ char* lp(void* base, int row, int cb, int rb) {
    return (char*)base + row * rb + (cb ^ ((row & 7) << 4));
}
// A-fragment (16x32 fp16) from swizzled LDS
__device__ __forceinline__ h16x8 lda(const void* base, int row, int kt, int rb, int lane) {
    return *(const h16x8*)((const char*)base + row * rb +
                           ((kt * 64 + ((lane >> 4) << 4)) ^ ((row & 7) << 4)));
}
// B-fragment from global weights W[N][K] fp16 row-major; kb = K*2 bytes
__device__ __forceinline__ h16x8 ldw(const _Float16* w, int nt, int kt, int kb, int lane) {
    return *(const h16x8*)((const char*)w + (nt * 16 + (lane & 15)) * kb +
                           kt * 64 + ((lane >> 4) << 4));
}

// ---------------- weight prep: fp32 -> fp16 in d_ws ----------------
__global__ __launch_bounds__(256) void k_prep_lin(const float* __restrict__ s,
                                                  _Float16* __restrict__ w, int n) {
    int i = blockIdx.x * 256 + threadIdx.x;
    if (i < n) w[i] = (_Float16)s[i];
}
// conv_w [3][64o][64d][5k] -> [3][5][64o][64d]
__global__ __launch_bounds__(256) void k_prep_conv(const float* __restrict__ s,
                                                   _Float16* __restrict__ w) {
    int t = blockIdx.x * 256 + threadIdx.x;
    if (t < DEPTH * 64 * 64 * K_) {
        int k = t % 5, d = (t / 5) % 64, o = (t / 320) % 64, i = t / 20480;
        w[((i * 5 + k) * 64 + o) * 64 + d] = (_Float16)s[t];
    }
}

// ---------------- encoder (runs once; fp32 VALU) ----------------
__global__ __launch_bounds__(256) void k_encoder(const float* __restrict__ xin,
                                                 const float* __restrict__ enc_w,
                                                 const float* __restrict__ enc_b,
                                                 float* __restrict__ psi) {
    const int b  = blockIdx.y;
    const int x0 = blockIdx.x * 64;
    __shared__ float s_x[TIN][64];
    __shared__ float s_w[TIN][H_];
    __shared__ float s_p[64][H_];
    const int tid = threadIdx.x;

    for (int idx = tid; idx < TIN * 64; idx += 256) {
        int t = idx >> 6, xl = idx & 63;
        s_x[t][xl] = xin[((size_t)b * TIN + t) * X_ + x0 + xl];
    }
    for (int idx = tid; idx < TIN * H_; idx += 256) {
        int t = idx >> 6, h = idx & 63;
        s_w[t][h] = enc_w[h * TIN + t];
    }
    __syncthreads();
    {
        int h = tid & 63, grp = tid >> 6;
        float bias = enc_b[h];
        for (int r = 0; r < 16; ++r) {
            int xl = grp * 16 + r;
            float acc = bias;
            #pragma unroll
            for (int t = 0; t < TIN; ++t) acc += s_x[t][xl] * s_w[t][h];
            s_p[xl][h] = acc;
        }
    }
    __syncthreads();
    {
        int lane = tid & 63, wv = tid >> 6;
        for (int r = 0; r < 16; ++r) {
            int xl = wv * 16 + r;
            float v = s_p[xl][lane];
            float s = v;
            #pragma unroll
            for (int off = 32; off; off >>= 1) s += __shfl_xor(s, off);
            float mu = s * (1.0f / 64.0f);
            float dv = v - mu;
            float q = dv * dv;
            #pragma unroll
            for (int off = 32; off; off >>= 1) q += __shfl_xor(q, off);
            float sd = sqrtf(q * (1.0f / 63.0f)) + 1e-6f;
            psi[((size_t)b * X_ + x0 + xl) * H_ + lane] = dv / sd;
        }
    }
}

// ---------------- fused layer: conv(K=5) -> MLP(64->128 gelu ->64) -> resid -> LN -> clip
// single-pass fp16 operands, fp32 accumulate; residual path exact fp32
__global__ __launch_bounds__(256, 4) void k_layer(const float* __restrict__ pin,
                                                  float* __restrict__ pout,
                                                  const _Float16* __restrict__ cw,  // [5][64][64]
                                                  const float* __restrict__ cb,
                                                  const _Float16* __restrict__ w1,  // [128][64]
                                                  const float* __restrict__ b1,
                                                  const _Float16* __restrict__ w2,  // [64][128]
                                                  const float* __restrict__ b2,
                                                  const float* __restrict__ g,
                                                  const float* __restrict__ bt) {
    __shared__ __align__(16) _Float16 sA[68 * 64];    // psi tile + halo
    __shared__ __align__(16) _Float16 sH[64 * 64];    // conv out
    __shared__ __align__(16) _Float16 sM[64 * 128];   // mlp1 out (gelu'd)

    const int tid  = threadIdx.x;
    const int b    = blockIdx.y;
    const int x0   = blockIdx.x * TILE;
    const int lane = tid & 63, wv = tid >> 6;
    const int wbase = wv * 16;
    const int l15 = lane & 15, l4 = lane >> 4;

    // ---- stage psi rows [x0-2, x0+66) as swizzled fp16
    for (int idx = tid; idx < 68 * 16; idx += 256) {
        int r = idx >> 4, c4 = idx & 15;
        int gx = x0 + r - 2;
        float4 v = make_float4(0.f, 0.f, 0.f, 0.f);
        if (gx >= 0 && gx < X_) v = *(const float4*)&pin[((size_t)b * X_ + gx) * H_ + c4 * 4];
        h16x4 hv;
        hv[0] = (_Float16)v.x; hv[1] = (_Float16)v.y;
        hv[2] = (_Float16)v.z; hv[3] = (_Float16)v.w;
        *(h16x4*)lp(sA, r, c4 * 8, 128) = hv;
    }
    __syncthreads();
    // everything below is wave-private (wave owns rows [wbase, wbase+16))

    // ---- conv: 5 shifted GEMMs, K=64 each
    f32x4 acc[4];
    #pragma unroll
    for (int nt = 0; nt < 4; ++nt) {
        float bb = cb[nt * 16 + l15];
        acc[nt] = (f32x4){bb, bb, bb, bb};
    }
    #pragma unroll
    for (int k = 0; k < K_; ++k) {
        #pragma unroll
        for (int kt = 0; kt < 2; ++kt) {
            h16x8 a = lda(sA, wbase + l15 + k, kt, 128, lane);
            #pragma unroll
            for (int nt = 0; nt < 4; ++nt) {
                h16x8 bf = ldw(cw + k * 4096, nt, kt, 128, lane);
                acc[nt] = __builtin_amdgcn_mfma_f32_16x16x32_f16(a, bf, acc[nt], 0, 0, 0);
            }
        }
    }
    #pragma unroll
    for (int nt = 0; nt < 4; ++nt) {
        int col = nt * 16 + l15;
        #pragma unroll
        for (int j = 0; j < 4; ++j) {
            int row = wbase + (l4 << 2) + j;
            *(_Float16*)lp(sH, row, col * 2, 128) = (_Float16)acc[nt][j];
        }
    }

    // ---- mlp1: [64]->[128], gelu
    f32x4 m8[8];
    #pragma unroll
    for (int nt = 0; nt < 8; ++nt) {
        float bb = b1[nt * 16 + l15];
        m8[nt] = (f32x4){bb, bb, bb, bb};
    }
    #pragma unroll
    for (int kt = 0; kt < 2; ++kt) {
        h16x8 a = lda(sH, wbase + l15, kt, 128, lane);
        #pragma unroll
        for (int nt = 0; nt < 8; ++nt) {
            h16x8 bf = ldw(w1, nt, kt, 128, lane);
            m8[nt] = __builtin_amdgcn_mfma_f32_16x16x32_f16(a, bf, m8[nt], 0, 0, 0);
        }
    }
    #pragma unroll
    for (int nt = 0; nt < 8; ++nt) {
        int col = nt * 16 + l15;
        #pragma unroll
        for (int j = 0; j < 4; ++j) {
            int row = wbase + (l4 << 2) + j;
            *(_Float16*)lp(sM, row, col * 2, 256) = (_Float16)gelu_exact(m8[nt][j]);
        }
    }

    // ---- mlp2: [128]->[64]
    f32x4 o4[4];
    #pragma unroll
    for (int nt = 0; nt < 4; ++nt) {
        float bb = b2[nt * 16 + l15];
        o4[nt] = (f32x4){bb, bb, bb, bb};
    }
    #pragma unroll
    for (int kt = 0; kt < 4; ++kt) {
        h16x8 a = lda(sM, wbase + l15, kt, 256, lane);
        #pragma unroll
        for (int nt = 0; nt < 4; ++nt) {
            h16x8 bf = ldw(w2, nt, kt, 256, lane);
            o4[nt] = __builtin_amdgcn_mfma_f32_16x16x32_f16(a, bf, o4[nt], 0, 0, 0);
        }
    }

    // ---- residual (re-read psi fp32) + LN + clip + store
    #pragma unroll
    for (int j = 0; j < 4; ++j) {
        int R = wbase + (l4 << 2) + j;
        size_t grow = ((size_t)b * X_ + x0 + R) * H_;
        float v[4];
        #pragma unroll
        for (int nt = 0; nt < 4; ++nt) v[nt] = o4[nt][j] + pin[grow + nt * 16 + l15];
        float s = v[0] + v[1] + v[2] + v[3];
        #pragma unroll
        for (int m = 1; m < 16; m <<= 1) s += __shfl_xor(s, m);
        float mu = s * (1.0f / 64.0f);
        float q = 0.f;
        #pragma unroll
        for (int nt = 0; nt < 4; ++nt) { v[nt] -= mu; q += v[nt] * v[nt]; }
        #pragma unroll
        for (int m = 1; m < 16; m <<= 1) q += __shfl_xor(q, m);
        float rs = rsqrtf(q * (1.0f / 64.0f) + 1e-5f);
        #pragma unroll
        for (int nt = 0; nt < 4; ++nt) {
            int col = nt * 16 + l15;
            float o = v[nt] * rs * g[col] + bt[col];
            o = fminf(10.0f, fmaxf(-10.0f, o));
            pout[grow + col] = o;
        }
    }
}

// ---------------- decoder head (fp16 single pass) ----------------
__global__ __launch_bounds__(256) void k_dec(const float* __restrict__ psi,
                                             const _Float16* __restrict__ d1,  // [64][64]
                                             const float* __restrict__ b1d,
                                             const float* __restrict__ w2d,
                                             const float* __restrict__ b2d,
                                             float* __restrict__ out, int step) {
    __shared__ __align__(16) _Float16 sD[64 * 64];
    const int tid  = threadIdx.x;
    const int b    = blockIdx.y;
    const int x0   = blockIdx.x * TILE;
    const int lane = tid & 63, wv = tid >> 6;
    const int wbase = wv * 16;
    const int l15 = lane & 15, l4 = lane >> 4;

    for (int idx = tid; idx < 64 * 16; idx += 256) {
        int r = idx >> 4, c4 = idx & 15;
        float4 v = *(const float4*)&psi[((size_t)b * X_ + x0 + r) * H_ + c4 * 4];
        h16x4 hv;
        hv[0] = (_Float16)v.x; hv[1] = (_Float16)v.y;
        hv[2] = (_Float16)v.z; hv[3] = (_Float16)v.w;
        *(h16x4*)lp(sD, r, c4 * 8, 128) = hv;
    }
    __syncthreads();

    f32x4 acc[4];
    #pragma unroll
    for (int nt = 0; nt < 4; ++nt) {
        float bb = b1d[nt * 16 + l15];
        acc[nt] = (f32x4){bb, bb, bb, bb};
    }
    #pragma unroll
    for (int kt = 0; kt < 2; ++kt) {
        h16x8 a = lda(sD, wbase + l15, kt, 128, lane);
        #pragma unroll
        for (int nt = 0; nt < 4; ++nt) {
            h16x8 bf = ldw(d1, nt, kt, 128, lane);
            acc[nt] = __builtin_amdgcn_mfma_f32_16x16x32_f16(a, bf, acc[nt], 0, 0, 0);
        }
    }
    float w2v[4];
    #pragma unroll
    for (int nt = 0; nt < 4; ++nt) w2v[nt] = w2d[nt * 16 + l15];
    float bb = b2d[0];
    #pragma unroll
    for (int j = 0; j < 4; ++j) {
        int R = wbase + (l4 << 2) + j;
        float s = 0.f;
        #pragma unroll
        for (int nt = 0; nt < 4; ++nt) s += gelu_exact(acc[nt][j]) * w2v[nt];
        #pragma unroll
        for (int m = 1; m < 16; m <<= 1) s += __shfl_xor(s, m);
        if (l15 == 0) out[((size_t)b * TOUT + step) * X_ + x0 + R] = s + bb;
    }
}

extern "C" void kernel_launch(void* const* d_in, const int* in_sizes, int n_in,
                              void* d_out, int out_size, void* d_ws, size_t ws_size,
                              hipStream_t stream) {
    const float* xin    = (const float*)d_in[0];
    const float* enc_w  = (const float*)d_in[1];
    const float* enc_b  = (const float*)d_in[2];
    const float* conv_w = (const float*)d_in[3];
    const float* conv_b = (const float*)d_in[4];
    const float* mlp_w1 = (const float*)d_in[5];
    const float* mlp_b1 = (const float*)d_in[6];
    const float* mlp_w2 = (const float*)d_in[7];
    const float* mlp_b2 = (const float*)d_in[8];
    const float* ln_g   = (const float*)d_in[9];
    const float* ln_b   = (const float*)d_in[10];
    const float* dec_w1 = (const float*)d_in[11];
    const float* dec_b1 = (const float*)d_in[12];
    const float* dec_w2 = (const float*)d_in[13];
    const float* dec_b2 = (const float*)d_in[14];
    float* out = (float*)d_out;

    const size_t PSI = (size_t)B_ * X_ * H_;
    float* psiA = (float*)d_ws;
    float* psiB = psiA + PSI;
    _Float16* cwf = (_Float16*)(psiB + PSI);  // [3][5][64][64]
    _Float16* w1f = cwf + 61440;              // [3][128][64]
    _Float16* w2f = w1f + 24576;              // [3][64][128]
    _Float16* d1f = w2f + 24576;              // [64][64]
    (void)ws_size; (void)n_in; (void)in_sizes; (void)out_size;

    k_prep_conv<<<240, 256, 0, stream>>>(conv_w, cwf);
    k_prep_lin<<<96, 256, 0, stream>>>(mlp_w1, w1f, 24576);
    k_prep_lin<<<96, 256, 0, stream>>>(mlp_w2, w2f, 24576);
    k_prep_lin<<<16, 256, 0, stream>>>(dec_w1, d1f, 4096);

    k_encoder<<<dim3(X_ / 64, B_), 256, 0, stream>>>(xin, enc_w, enc_b, psiA);

    const float* cur = psiA;
    float* nxt = psiB;
    for (int t = 0; t < TOUT; ++t) {
        for (int i = 0; i < DEPTH; ++i) {
            k_layer<<<dim3(X_ / TILE, B_), 256, 0, stream>>>(
                cur, nxt,
                cwf + i * 20480, conv_b + i * H_,
                w1f + i * 8192,  mlp_b1 + i * F_,
                w2f + i * 8192,  mlp_b2 + i * H_,
                ln_g + i * H_, ln_b + i * H_);
            float* tmp = (float*)cur; cur = nxt; nxt = tmp;
        }
        k_dec<<<dim3(X_ / TILE, B_), 256, 0, stream>>>(cur, d1f, dec_b1, dec_w2, dec_b2, out, t);
    }
}

// Round 4
// 11029.997 us; speedup vs baseline: 5.6528x; 1.3324x over previous
//
#include <hip/hip_runtime.h>
#include <hip/hip_bf16.h>

#define B_   32
#define TIN  16
#define X_   8192
#define H_   64
#define F_   128
#define K_   5
#define DEPTH 3
#define TOUT 32
#define TILE 128          // k_layer tile (4 waves x 32 rows)
#define TILE_D 64         // k_dec tile

typedef __attribute__((ext_vector_type(8))) _Float16 h16x8;
typedef __attribute__((ext_vector_type(4))) _Float16 h16x4;
typedef __attribute__((ext_vector_type(4))) float f32x4;

__device__ __forceinline__ float gelu_exact(float z) {
    return 0.5f * z * (1.0f + erff(z * 0.70710678118654752f));
}

// swizzled LDS address: row stride rb bytes, XOR (row&7)<<4 kills 128B-stride bank conflicts
__device__ __forceinline__ char* lp(void* base, int row, int cb, int rb) {
    return (char*)base + row * rb + (cb ^ ((row & 7) << 4));
}
// A-fragment (16x32 fp16) from swizzled LDS
__device__ __forceinline__ h16x8 lda(const void* base, int row, int kt, int rb, int lane) {
    return *(const h16x8*)((const char*)base + row * rb +
                           ((kt * 64 + ((lane >> 4) << 4)) ^ ((row & 7) << 4)));
}
// B-fragment from global weights W[N][K] fp16 row-major; kb = K*2 bytes
__device__ __forceinline__ h16x8 ldw(const _Float16* w, int nt, int kt, int kb, int lane) {
    return *(const h16x8*)((const char*)w + (nt * 16 + (lane & 15)) * kb +
                           kt * 64 + ((lane >> 4) << 4));
}

// ---------------- weight prep: fp32 -> fp16 in d_ws ----------------
__global__ __launch_bounds__(256) void k_prep_lin(const float* __restrict__ s,
                                                  _Float16* __restrict__ w, int n) {
    int i = blockIdx.x * 256 + threadIdx.x;
    if (i < n) w[i] = (_Float16)s[i];
}
// conv_w [3][64o][64d][5k] -> [3][5][64o][64d]
__global__ __launch_bounds__(256) void k_prep_conv(const float* __restrict__ s,
                                                   _Float16* __restrict__ w) {
    int t = blockIdx.x * 256 + threadIdx.x;
    if (t < DEPTH * 64 * 64 * K_) {
        int k = t % 5, d = (t / 5) % 64, o = (t / 320) % 64, i = t / 20480;
        w[((i * 5 + k) * 64 + o) * 64 + d] = (_Float16)s[t];
    }
}

// ---------------- encoder (runs once; fp32 VALU) ----------------
__global__ __launch_bounds__(256) void k_encoder(const float* __restrict__ xin,
                                                 const float* __restrict__ enc_w,
                                                 const float* __restrict__ enc_b,
                                                 float* __restrict__ psi) {
    const int b  = blockIdx.y;
    const int x0 = blockIdx.x * 64;
    __shared__ float s_x[TIN][64];
    __shared__ float s_w[TIN][H_];
    __shared__ float s_p[64][H_];
    const int tid = threadIdx.x;

    for (int idx = tid; idx < TIN * 64; idx += 256) {
        int t = idx >> 6, xl = idx & 63;
        s_x[t][xl] = xin[((size_t)b * TIN + t) * X_ + x0 + xl];
    }
    for (int idx = tid; idx < TIN * H_; idx += 256) {
        int t = idx >> 6, h = idx & 63;
        s_w[t][h] = enc_w[h * TIN + t];
    }
    __syncthreads();
    {
        int h = tid & 63, grp = tid >> 6;
        float bias = enc_b[h];
        for (int r = 0; r < 16; ++r) {
            int xl = grp * 16 + r;
            float acc = bias;
            #pragma unroll
            for (int t = 0; t < TIN; ++t) acc += s_x[t][xl] * s_w[t][h];
            s_p[xl][h] = acc;
        }
    }
    __syncthreads();
    {
        int lane = tid & 63, wv = tid >> 6;
        for (int r = 0; r < 16; ++r) {
            int xl = wv * 16 + r;
            float v = s_p[xl][lane];
            float s = v;
            #pragma unroll
            for (int off = 32; off; off >>= 1) s += __shfl_xor(s, off);
            float mu = s * (1.0f / 64.0f);
            float dv = v - mu;
            float q = dv * dv;
            #pragma unroll
            for (int off = 32; off; off >>= 1) q += __shfl_xor(q, off);
            float sd = sqrtf(q * (1.0f / 63.0f)) + 1e-6f;
            psi[((size_t)b * X_ + x0 + xl) * H_ + lane] = dv / sd;
        }
    }
}

// ---------------- fused layer, M=32/wave: conv(K=5) -> MLP -> resid -> LN -> clip
__global__ __launch_bounds__(256, 2) void k_layer(const float* __restrict__ pin,
                                                  float* __restrict__ pout,
                                                  const _Float16* __restrict__ cw,  // [5][64][64]
                                                  const float* __restrict__ cb,
                                                  const _Float16* __restrict__ w1,  // [128][64]
                                                  const float* __restrict__ b1,
                                                  const _Float16* __restrict__ w2,  // [64][128]
                                                  const float* __restrict__ b2,
                                                  const float* __restrict__ g,
                                                  const float* __restrict__ bt) {
    __shared__ __align__(16) _Float16 sA[(TILE + 4) * 64];   // psi tile + halo (132 rows)
    __shared__ __align__(16) _Float16 sH[TILE * 64];         // conv out
    __shared__ __align__(16) _Float16 sM[TILE * 128];        // mlp1 out (gelu'd)

    const int tid  = threadIdx.x;
    const int b    = blockIdx.y;
    const int x0   = blockIdx.x * TILE;
    const int lane = tid & 63, wv = tid >> 6;
    const int R0   = wv * 32;                // wave owns output rows [R0, R0+32)
    const int l15  = lane & 15, l4 = lane >> 4;

    // ---- stage psi rows [x0-2, x0+TILE+2) as swizzled fp16
    for (int idx = tid; idx < (TILE + 4) * 16; idx += 256) {
        int r = idx >> 4, c4 = idx & 15;
        int gx = x0 + r - 2;
        float4 v = make_float4(0.f, 0.f, 0.f, 0.f);
        if (gx >= 0 && gx < X_) v = *(const float4*)&pin[((size_t)b * X_ + gx) * H_ + c4 * 4];
        h16x4 hv;
        hv[0] = (_Float16)v.x; hv[1] = (_Float16)v.y;
        hv[2] = (_Float16)v.z; hv[3] = (_Float16)v.w;
        *(h16x4*)lp(sA, r, c4 * 8, 128) = hv;
    }
    __syncthreads();
    // everything below is wave-private (wave owns rows [R0, R0+32))

    // ---- conv: 5 shifted GEMMs, K=64 each; B-frags shared across 2 row-blocks
    f32x4 acc0[4], acc1[4];
    #pragma unroll
    for (int nt = 0; nt < 4; ++nt) {
        float bb = cb[nt * 16 + l15];
        acc0[nt] = (f32x4){bb, bb, bb, bb};
        acc1[nt] = acc0[nt];
    }
    #pragma unroll
    for (int k = 0; k < K_; ++k) {
        #pragma unroll
        for (int kt = 0; kt < 2; ++kt) {
            h16x8 a0 = lda(sA, R0 + l15 + k,      kt, 128, lane);
            h16x8 a1 = lda(sA, R0 + 16 + l15 + k, kt, 128, lane);
            #pragma unroll
            for (int nt = 0; nt < 4; ++nt) {
                h16x8 bf = ldw(cw + k * 4096, nt, kt, 128, lane);
                acc0[nt] = __builtin_amdgcn_mfma_f32_16x16x32_f16(a0, bf, acc0[nt], 0, 0, 0);
                acc1[nt] = __builtin_amdgcn_mfma_f32_16x16x32_f16(a1, bf, acc1[nt], 0, 0, 0);
            }
        }
    }
    #pragma unroll
    for (int nt = 0; nt < 4; ++nt) {
        int col = nt * 16 + l15;
        #pragma unroll
        for (int j = 0; j < 4; ++j) {
            int r0 = R0 + (l4 << 2) + j;
            *(_Float16*)lp(sH, r0,      col * 2, 128) = (_Float16)acc0[nt][j];
            *(_Float16*)lp(sH, r0 + 16, col * 2, 128) = (_Float16)acc1[nt][j];
        }
    }

    // ---- mlp1: [64]->[128], gelu
    f32x4 m0[8], m1[8];
    #pragma unroll
    for (int nt = 0; nt < 8; ++nt) {
        float bb = b1[nt * 16 + l15];
        m0[nt] = (f32x4){bb, bb, bb, bb};
        m1[nt] = m0[nt];
    }
    #pragma unroll
    for (int kt = 0; kt < 2; ++kt) {
        h16x8 a0 = lda(sH, R0 + l15,      kt, 128, lane);
        h16x8 a1 = lda(sH, R0 + 16 + l15, kt, 128, lane);
        #pragma unroll
        for (int nt = 0; nt < 8; ++nt) {
            h16x8 bf = ldw(w1, nt, kt, 128, lane);
            m0[nt] = __builtin_amdgcn_mfma_f32_16x16x32_f16(a0, bf, m0[nt], 0, 0, 0);
            m1[nt] = __builtin_amdgcn_mfma_f32_16x16x32_f16(a1, bf, m1[nt], 0, 0, 0);
        }
    }
    #pragma unroll
    for (int nt = 0; nt < 8; ++nt) {
        int col = nt * 16 + l15;
        #pragma unroll
        for (int j = 0; j < 4; ++j) {
            int r0 = R0 + (l4 << 2) + j;
            *(_Float16*)lp(sM, r0,      col * 2, 256) = (_Float16)gelu_exact(m0[nt][j]);
            *(_Float16*)lp(sM, r0 + 16, col * 2, 256) = (_Float16)gelu_exact(m1[nt][j]);
        }
    }

    // ---- mlp2: [128]->[64]
    f32x4 o0[4], o1[4];
    #pragma unroll
    for (int nt = 0; nt < 4; ++nt) {
        float bb = b2[nt * 16 + l15];
        o0[nt] = (f32x4){bb, bb, bb, bb};
        o1[nt] = o0[nt];
    }
    #pragma unroll
    for (int kt = 0; kt < 4; ++kt) {
        h16x8 a0 = lda(sM, R0 + l15,      kt, 256, lane);
        h16x8 a1 = lda(sM, R0 + 16 + l15, kt, 256, lane);
        #pragma unroll
        for (int nt = 0; nt < 4; ++nt) {
            h16x8 bf = ldw(w2, nt, kt, 256, lane);
            o0[nt] = __builtin_amdgcn_mfma_f32_16x16x32_f16(a0, bf, o0[nt], 0, 0, 0);
            o1[nt] = __builtin_amdgcn_mfma_f32_16x16x32_f16(a1, bf, o1[nt], 0, 0, 0);
        }
    }

    // ---- residual (re-read psi fp32) + LN + clip + store, both row-blocks
    #pragma unroll
    for (int j = 0; j < 4; ++j) {
        int R = R0 + (l4 << 2) + j;
        size_t grow = ((size_t)b * X_ + x0 + R) * H_;
        float v[4];
        #pragma unroll
        for (int nt = 0; nt < 4; ++nt) v[nt] = o0[nt][j] + pin[grow + nt * 16 + l15];
        float s = v[0] + v[1] + v[2] + v[3];
        #pragma unroll
        for (int m = 1; m < 16; m <<= 1) s += __shfl_xor(s, m);
        float mu = s * (1.0f / 64.0f);
        float q = 0.f;
        #pragma unroll
        for (int nt = 0; nt < 4; ++nt) { v[nt] -= mu; q += v[nt] * v[nt]; }
        #pragma unroll
        for (int m = 1; m < 16; m <<= 1) q += __shfl_xor(q, m);
        float rs = rsqrtf(q * (1.0f / 64.0f) + 1e-5f);
        #pragma unroll
        for (int nt = 0; nt < 4; ++nt) {
            int col = nt * 16 + l15;
            float o = v[nt] * rs * g[col] + bt[col];
            o = fminf(10.0f, fmaxf(-10.0f, o));
            pout[grow + col] = o;
        }
    }
    #pragma unroll
    for (int j = 0; j < 4; ++j) {
        int R = R0 + 16 + (l4 << 2) + j;
        size_t grow = ((size_t)b * X_ + x0 + R) * H_;
        float v[4];
        #pragma unroll
        for (int nt = 0; nt < 4; ++nt) v[nt] = o1[nt][j] + pin[grow + nt * 16 + l15];
        float s = v[0] + v[1] + v[2] + v[3];
        #pragma unroll
        for (int m = 1; m < 16; m <<= 1) s += __shfl_xor(s, m);
        float mu = s * (1.0f / 64.0f);
        float q = 0.f;
        #pragma unroll
        for (int nt = 0; nt < 4; ++nt) { v[nt] -= mu; q += v[nt] * v[nt]; }
        #pragma unroll
        for (int m = 1; m < 16; m <<= 1) q += __shfl_xor(q, m);
        float rs = rsqrtf(q * (1.0f / 64.0f) + 1e-5f);
        #pragma unroll
        for (int nt = 0; nt < 4; ++nt) {
            int col = nt * 16 + l15;
            float o = v[nt] * rs * g[col] + bt[col];
            o = fminf(10.0f, fmaxf(-10.0f, o));
            pout[grow + col] = o;
        }
    }
}

// ---------------- decoder head (fp16 single pass) ----------------
__global__ __launch_bounds__(256) void k_dec(const float* __restrict__ psi,
                                             const _Float16* __restrict__ d1,  // [64][64]
                                             const float* __restrict__ b1d,
                                             const float* __restrict__ w2d,
                                             const float* __restrict__ b2d,
                                             float* __restrict__ out, int step) {
    __shared__ __align__(16) _Float16 sD[64 * 64];
    const int tid  = threadIdx.x;
    const int b    = blockIdx.y;
    const int x0   = blockIdx.x * TILE_D;
    const int lane = tid & 63, wv = tid >> 6;
    const int wbase = wv * 16;
    const int l15 = lane & 15, l4 = lane >> 4;

    for (int idx = tid; idx < 64 * 16; idx += 256) {
        int r = idx >> 4, c4 = idx & 15;
        float4 v = *(const float4*)&psi[((size_t)b * X_ + x0 + r) * H_ + c4 * 4];
        h16x4 hv;
        hv[0] = (_Float16)v.x; hv[1] = (_Float16)v.y;
        hv[2] = (_Float16)v.z; hv[3] = (_Float16)v.w;
        *(h16x4*)lp(sD, r, c4 * 8, 128) = hv;
    }
    __syncthreads();

    f32x4 acc[4];
    #pragma unroll
    for (int nt = 0; nt < 4; ++nt) {
        float bb = b1d[nt * 16 + l15];
        acc[nt] = (f32x4){bb, bb, bb, bb};
    }
    #pragma unroll
    for (int kt = 0; kt < 2; ++kt) {
        h16x8 a = lda(sD, wbase + l15, kt, 128, lane);
        #pragma unroll
        for (int nt = 0; nt < 4; ++nt) {
            h16x8 bf = ldw(d1, nt, kt, 128, lane);
            acc[nt] = __builtin_amdgcn_mfma_f32_16x16x32_f16(a, bf, acc[nt], 0, 0, 0);
        }
    }
    float w2v[4];
    #pragma unroll
    for (int nt = 0; nt < 4; ++nt) w2v[nt] = w2d[nt * 16 + l15];
    float bb = b2d[0];
    #pragma unroll
    for (int j = 0; j < 4; ++j) {
        int R = wbase + (l4 << 2) + j;
        float s = 0.f;
        #pragma unroll
        for (int nt = 0; nt < 4; ++nt) s += gelu_exact(acc[nt][j]) * w2v[nt];
        #pragma unroll
        for (int m = 1; m < 16; m <<= 1) s += __shfl_xor(s, m);
        if (l15 == 0) out[((size_t)b * TOUT + step) * X_ + x0 + R] = s + bb;
    }
}

extern "C" void kernel_launch(void* const* d_in, const int* in_sizes, int n_in,
                              void* d_out, int out_size, void* d_ws, size_t ws_size,
                              hipStream_t stream) {
    const float* xin    = (const float*)d_in[0];
    const float* enc_w  = (const float*)d_in[1];
    const float* enc_b  = (const float*)d_in[2];
    const float* conv_w = (const float*)d_in[3];
    const float* conv_b = (const float*)d_in[4];
    const float* mlp_w1 = (const float*)d_in[5];
    const float* mlp_b1 = (const float*)d_in[6];
    const float* mlp_w2 = (const float*)d_in[7];
    const float* mlp_b2 = (const float*)d_in[8];
    const float* ln_g   = (const float*)d_in[9];
    const float* ln_b   = (const float*)d_in[10];
    const float* dec_w1 = (const float*)d_in[11];
    const float* dec_b1 = (const float*)d_in[12];
    const float* dec_w2 = (const float*)d_in[13];
    const float* dec_b2 = (const float*)d_in[14];
    float* out = (float*)d_out;

    const size_t PSI = (size_t)B_ * X_ * H_;
    float* psiA = (float*)d_ws;
    float* psiB = psiA + PSI;
    _Float16* cwf = (_Float16*)(psiB + PSI);  // [3][5][64][64]
    _Float16* w1f = cwf + 61440;              // [3][128][64]
    _Float16* w2f = w1f + 24576;              // [3][64][128]
    _Float16* d1f = w2f + 24576;              // [64][64]
    (void)ws_size; (void)n_in; (void)in_sizes; (void)out_size;

    k_prep_conv<<<240, 256, 0, stream>>>(conv_w, cwf);
    k_prep_lin<<<96, 256, 0, stream>>>(mlp_w1, w1f, 24576);
    k_prep_lin<<<96, 256, 0, stream>>>(mlp_w2, w2f, 24576);
    k_prep_lin<<<16, 256, 0, stream>>>(dec_w1, d1f, 4096);

    k_encoder<<<dim3(X_ / 64, B_), 256, 0, stream>>>(xin, enc_w, enc_b, psiA);

    const float* cur = psiA;
    float* nxt = psiB;
    for (int t = 0; t < TOUT; ++t) {
        for (int i = 0; i < DEPTH; ++i) {
            k_layer<<<dim3(X_ / TILE, B_), 256, 0, stream>>>(
                cur, nxt,
                cwf + i * 20480, conv_b + i * H_,
                w1f + i * 8192,  mlp_b1 + i * F_,
                w2f + i * 8192,  mlp_b2 + i * H_,
                ln_g + i * H_, ln_b + i * H_);
            float* tmp = (float*)cur; cur = nxt; nxt = tmp;
        }
        k_dec<<<dim3(X_ / TILE_D, B_), 256, 0, stream>>>(cur, d1f, dec_b1, dec_w2, dec_b2, out, t);
    }
}